// Round 3
// baseline (1304.294 us; speedup 1.0000x reference)
//
#include <hip/hip_runtime.h>
#include <stdint.h>

typedef _Float16 half8 __attribute__((ext_vector_type(8)));
typedef float float4v __attribute__((ext_vector_type(4)));

// Problem constants
constexpr int kN = 100000;   // nodes
constexpr int kE = 1600000;  // edges
constexpr int kP = 500000;   // pairs
constexpr int NBS = (kN + 255) / 256;  // scan blocks = 391
constexpr int CTILES = kN / 16;        // 6250 conv wave-tiles (exact)
constexpr int DTILES = kP / 16;        // 31250 decoder wave-tiles (exact)

// ---------------------------------------------------------------------------
// CSR build
// ---------------------------------------------------------------------------
__global__ void deg_kernel(const int* __restrict__ dst, int* __restrict__ deg) {
    int e = blockIdx.x * blockDim.x + threadIdx.x;
    if (e < kE) atomicAdd(&deg[dst[e]], 1);
}

__global__ void scan_block_sums(const int* __restrict__ deg, int* __restrict__ bsum) {
    __shared__ int red[256];
    int t = threadIdx.x;
    int i = blockIdx.x * 256 + t;
    red[t] = (i < kN) ? deg[i] : 0;
    __syncthreads();
    for (int s = 128; s > 0; s >>= 1) {
        if (t < s) red[t] += red[t + s];
        __syncthreads();
    }
    if (t == 0) bsum[blockIdx.x] = red[0];
}

__global__ void scan_bsums(const int* __restrict__ bsum, int* __restrict__ boff) {
    __shared__ int sm[512];
    int t = threadIdx.x;
    int orig = (t < NBS) ? bsum[t] : 0;
    sm[t] = orig;
    __syncthreads();
    for (int d = 1; d < 512; d <<= 1) {
        int u = (t >= d) ? sm[t - d] : 0;
        __syncthreads();
        sm[t] += u;
        __syncthreads();
    }
    if (t < NBS) boff[t] = sm[t] - orig;  // exclusive
}

__global__ void scan_write(const int* __restrict__ deg, const int* __restrict__ boff,
                           int* __restrict__ row_start, int* __restrict__ cursor) {
    __shared__ int sm[256];
    int t = threadIdx.x;
    int i = blockIdx.x * 256 + t;
    int v = (i < kN) ? deg[i] : 0;
    sm[t] = v;
    __syncthreads();
    for (int d = 1; d < 256; d <<= 1) {
        int u = (t >= d) ? sm[t - d] : 0;
        __syncthreads();
        sm[t] += u;
        __syncthreads();
    }
    int excl = sm[t] - v + boff[blockIdx.x];
    if (i < kN) { row_start[i] = excl; cursor[i] = excl; }
    if (i == kN - 1) row_start[kN] = excl + v;
}

__global__ void fill_kernel(const int* __restrict__ src, const int* __restrict__ dst,
                            int* __restrict__ cursor, int* __restrict__ srcs) {
    int e = blockIdx.x * blockDim.x + threadIdx.x;
    if (e < kE) {
        int p = atomicAdd(&cursor[dst[e]], 1);
        srcs[p] = src[e];
    }
}

// ---------------------------------------------------------------------------
// Prep: x -> fp16; weights -> combined fp16 hi/lo planes
// ---------------------------------------------------------------------------
__global__ void cvt_x_kernel(const float* __restrict__ x, _Float16* __restrict__ xh) {
    const int i = (blockIdx.x * 256 + threadIdx.x) * 8;
    if (i >= kN * 128) return;
    const float4 a = *(const float4*)&x[i];
    const float4 b = *(const float4*)&x[i + 4];
    half8 v;
    v[0] = (_Float16)a.x; v[1] = (_Float16)a.y; v[2] = (_Float16)a.z; v[3] = (_Float16)a.w;
    v[4] = (_Float16)b.x; v[5] = (_Float16)b.y; v[6] = (_Float16)b.z; v[7] = (_Float16)b.w;
    *(half8*)&xh[i] = v;
}

// CW1/CW2: [128 out][256 k], k<128 -> Wl, k>=128 -> Wr. M1:[128][128], M2:[64][128].
__global__ void cvt_w_kernel(
    const float* __restrict__ W1l, const float* __restrict__ W1r,
    const float* __restrict__ W2l, const float* __restrict__ W2r,
    const float* __restrict__ Wm1, const float* __restrict__ Wm2,
    _Float16* __restrict__ CW1h, _Float16* __restrict__ CW1e,
    _Float16* __restrict__ CW2h, _Float16* __restrict__ CW2e,
    _Float16* __restrict__ M1h,  _Float16* __restrict__ M1e,
    _Float16* __restrict__ M2h,  _Float16* __restrict__ M2e)
{
    const int i = blockIdx.x * 256 + threadIdx.x;
    float w;
    _Float16 *ph, *pe;
    if (i < 32768) {
        const int o = i >> 8, k = i & 255;
        w = (k < 128) ? W1l[o * 128 + k] : W1r[o * 128 + k - 128];
        ph = CW1h + i; pe = CW1e + i;
    } else if (i < 65536) {
        const int j = i - 32768;
        const int o = j >> 8, k = j & 255;
        w = (k < 128) ? W2l[o * 128 + k] : W2r[o * 128 + k - 128];
        ph = CW2h + j; pe = CW2e + j;
    } else if (i < 81920) {
        const int j = i - 65536;
        w = Wm1[j]; ph = M1h + j; pe = M1e + j;
    } else if (i < 90112) {
        const int j = i - 81920;
        w = Wm2[j]; ph = M2h + j; pe = M2e + j;
    } else return;
    const _Float16 h = (_Float16)w;
    *ph = h;
    *pe = (_Float16)(w - (float)h);
}

// ---------------------------------------------------------------------------
// Wave-autonomous fused SAGEConv. One wave = 16 nodes, no __syncthreads.
// Lane (p = l&15, q = l>>4) accumulates node p's mean over dims {kt*32+q*8},
// kt=0..3, directly in registers (fp32), then MFMA with K=256 = [mean|root].
// LDS: per-wave epilogue staging slice [16][136] fp16 (4.4 KB/wave).
// ---------------------------------------------------------------------------
template <bool RELU>
__global__ __launch_bounds__(256, 3) void conv_mfma(
    const _Float16* __restrict__ xin,
    const int* __restrict__ row_start,
    const int* __restrict__ srcs,
    const _Float16* __restrict__ Wh,  // [128][256] fp16 hi
    const _Float16* __restrict__ We,  // [128][256] fp16 lo
    const float* __restrict__ bias,
    _Float16* __restrict__ out)
{
    __shared__ __align__(16) _Float16 stg_all[4 * 16 * 136];
    const int wInB = threadIdx.x >> 6;
    _Float16* stg  = &stg_all[wInB * (16 * 136)];
    const int l = threadIdx.x & 63;
    const int p = l & 15;
    const int q = l >> 4;
    const int tile = blockIdx.x * 4 + wInB;
    if (tile >= CTILES) return;
    const int n = tile * 16 + p;   // this lane's node

    // Root row chunks (issued early, independent)
    const _Float16* rowp = &xin[(size_t)n * 128 + q * 8];
    half8 rt[4];
#pragma unroll
    for (int kt = 0; kt < 4; kt++) rt[kt] = *(const half8*)(rowp + kt * 32);

    // Gather-mean into fp32 registers, 2x neighbor unroll for MLP
    const int j0 = row_start[n], j1 = row_start[n + 1];
    float acc[4][8];
#pragma unroll
    for (int kt = 0; kt < 4; kt++)
#pragma unroll
        for (int u = 0; u < 8; u++) acc[kt][u] = 0.f;

    int j = j0;
    for (; j + 2 <= j1; j += 2) {
        const int s0 = srcs[j], s1 = srcs[j + 1];
        const _Float16* r0 = &xin[(size_t)s0 * 128 + q * 8];
        const _Float16* r1 = &xin[(size_t)s1 * 128 + q * 8];
        half8 v0[4], v1[4];
#pragma unroll
        for (int kt = 0; kt < 4; kt++) v0[kt] = *(const half8*)(r0 + kt * 32);
#pragma unroll
        for (int kt = 0; kt < 4; kt++) v1[kt] = *(const half8*)(r1 + kt * 32);
#pragma unroll
        for (int kt = 0; kt < 4; kt++)
#pragma unroll
            for (int u = 0; u < 8; u++) {
                acc[kt][u] += (float)v0[kt][u];
                acc[kt][u] += (float)v1[kt][u];
            }
    }
    if (j < j1) {
        const int s0 = srcs[j];
        const _Float16* r0 = &xin[(size_t)s0 * 128 + q * 8];
#pragma unroll
        for (int kt = 0; kt < 4; kt++) {
            const half8 v0 = *(const half8*)(r0 + kt * 32);
#pragma unroll
            for (int u = 0; u < 8; u++) acc[kt][u] += (float)v0[u];
        }
    }
    const int dg = j1 - j0;
    const float inv = 1.0f / (float)(dg > 1 ? dg : 1);
    half8 am[4];
#pragma unroll
    for (int kt = 0; kt < 4; kt++)
#pragma unroll
        for (int u = 0; u < 8; u++) am[kt][u] = (_Float16)(acc[kt][u] * inv);

    // MFMA: D[16][128] = A[16][256] @ CW[128][256]^T  (hi+lo planes)
    float4v accC[8];
#pragma unroll
    for (int nt = 0; nt < 8; nt++) {
        const float b = bias[nt * 16 + p];
        accC[nt][0] = b; accC[nt][1] = b; accC[nt][2] = b; accC[nt][3] = b;
    }
#pragma unroll
    for (int kt = 0; kt < 8; kt++) {
        const half8 a = (kt < 4) ? am[kt] : rt[kt - 4];
#pragma unroll
        for (int nt = 0; nt < 8; nt++) {
            const int widx = (nt * 16 + p) * 256 + kt * 32 + q * 8;
            const half8 bh = *(const half8*)&Wh[widx];
            const half8 be = *(const half8*)&We[widx];
            accC[nt] = __builtin_amdgcn_mfma_f32_16x16x32_f16(a, bh, accC[nt], 0, 0, 0);
            accC[nt] = __builtin_amdgcn_mfma_f32_16x16x32_f16(a, be, accC[nt], 0, 0, 0);
        }
    }

    // Epilogue: C-layout -> per-wave LDS slice -> row-major global (fp16)
#pragma unroll
    for (int nt = 0; nt < 8; nt++)
#pragma unroll
        for (int r = 0; r < 4; r++) {
            float v = accC[nt][r];
            if (RELU) v = fmaxf(v, 0.f);
            stg[(q * 4 + r) * 136 + nt * 16 + p] = (_Float16)v;
        }
    // same-wave DS ops are in-order: reads below see the writes above
    {
        const int row = l >> 2;           // 0..15
        const int c   = (l & 3) * 8;      // 0,8,16,24
        _Float16* orow = &out[(size_t)(tile * 16 + row) * 128];
#pragma unroll
        for (int i = 0; i < 4; i++)
            *(half8*)(orow + i * 32 + c) = *(const half8*)&stg[row * 136 + i * 32 + c];
    }
}

// ---------------------------------------------------------------------------
// Wave-autonomous fused decoder. One wave = 16 pairs, persistent grid-stride,
// register-prefetch of next tile's z-row gathers. hp is built directly in
// MFMA A-frag layout (no LDS). Only y1 C->A transform uses a per-wave slice.
// ---------------------------------------------------------------------------
__global__ __launch_bounds__(256, 3) void decoder_mfma(
    const _Float16* __restrict__ z,
    const int* __restrict__ pairs,
    const _Float16* __restrict__ M1h, const _Float16* __restrict__ M1e,
    const float* __restrict__ bm1,
    const _Float16* __restrict__ M2h, const _Float16* __restrict__ M2e,
    const float* __restrict__ bm2,
    const float* __restrict__ Wm3, const float* __restrict__ bm3,
    float* __restrict__ outv)
{
    __shared__ __align__(16) _Float16 y1s_all[4 * 16 * 136];
    const int wInB = threadIdx.x >> 6;
    _Float16* y1s  = &y1s_all[wInB * (16 * 136)];
    const int l = threadIdx.x & 63;
    const int p = l & 15;
    const int q = l >> 4;
    const int wid = blockIdx.x * 4 + wInB;
    const int nw  = gridDim.x * 4;

    int tile = wid;
    if (tile >= DTILES) return;

    const float b3 = bm3[0];
    float wm3v[4], bm1v[8], bm2v[4];
#pragma unroll
    for (int nt = 0; nt < 4; nt++) wm3v[nt] = Wm3[nt * 16 + p];
#pragma unroll
    for (int nt = 0; nt < 8; nt++) bm1v[nt] = bm1[nt * 16 + p];
#pragma unroll
    for (int nt = 0; nt < 4; nt++) bm2v[nt] = bm2[nt * 16 + p];

    // Prologue: indices + row gathers for first tile
    int2 ab = *(const int2*)&pairs[(size_t)(tile * 16 + p) * 2];
    half8 za[4], zb[4];
#pragma unroll
    for (int kt = 0; kt < 4; kt++) {
        za[kt] = *(const half8*)&z[(size_t)ab.x * 128 + kt * 32 + q * 8];
        zb[kt] = *(const half8*)&z[(size_t)ab.y * 128 + kt * 32 + q * 8];
    }

    while (true) {
        const int next = tile + nw;
        const bool more = (next < DTILES);
        int2 abn;
        if (more) abn = *(const int2*)&pairs[(size_t)(next * 16 + p) * 2];

        // hp frags: elementwise fp16 product, already in A-frag layout
        half8 a1[4];
#pragma unroll
        for (int kt = 0; kt < 4; kt++) a1[kt] = za[kt] * zb[kt];

        // L1: y1 = relu(hp @ M1^T + bm1), N=128
        float4v acc1[8];
#pragma unroll
        for (int nt = 0; nt < 8; nt++) {
            const float b = bm1v[nt];
            acc1[nt][0] = b; acc1[nt][1] = b; acc1[nt][2] = b; acc1[nt][3] = b;
        }
#pragma unroll
        for (int kt = 0; kt < 4; kt++)
#pragma unroll
            for (int nt = 0; nt < 8; nt++) {
                const int widx = (nt * 16 + p) * 128 + kt * 32 + q * 8;
                const half8 bh = *(const half8*)&M1h[widx];
                const half8 be = *(const half8*)&M1e[widx];
                acc1[nt] = __builtin_amdgcn_mfma_f32_16x16x32_f16(a1[kt], bh, acc1[nt], 0, 0, 0);
                acc1[nt] = __builtin_amdgcn_mfma_f32_16x16x32_f16(a1[kt], be, acc1[nt], 0, 0, 0);
            }

        // Prefetch next tile's z rows (fly during LDS transform + L2 + dot)
        half8 zan[4], zbn[4];
        if (more) {
#pragma unroll
            for (int kt = 0; kt < 4; kt++) {
                zan[kt] = *(const half8*)&z[(size_t)abn.x * 128 + kt * 32 + q * 8];
                zbn[kt] = *(const half8*)&z[(size_t)abn.y * 128 + kt * 32 + q * 8];
            }
        }

        // y1 C-layout -> per-wave LDS -> A-frag (same-wave DS is in-order)
#pragma unroll
        for (int nt = 0; nt < 8; nt++)
#pragma unroll
            for (int r = 0; r < 4; r++)
                y1s[(q * 4 + r) * 136 + nt * 16 + p] = (_Float16)fmaxf(acc1[nt][r], 0.f);
        half8 a2[4];
#pragma unroll
        for (int kt = 0; kt < 4; kt++)
            a2[kt] = *(const half8*)&y1s[p * 136 + kt * 32 + q * 8];

        // L2: y2 = relu(y1 @ M2^T + bm2), N=64
        float4v acc2[4];
#pragma unroll
        for (int nt = 0; nt < 4; nt++) {
            const float b = bm2v[nt];
            acc2[nt][0] = b; acc2[nt][1] = b; acc2[nt][2] = b; acc2[nt][3] = b;
        }
#pragma unroll
        for (int kt = 0; kt < 4; kt++)
#pragma unroll
            for (int nt = 0; nt < 4; nt++) {
                const int widx = (nt * 16 + p) * 128 + kt * 32 + q * 8;
                const half8 bh = *(const half8*)&M2h[widx];
                const half8 be = *(const half8*)&M2e[widx];
                acc2[nt] = __builtin_amdgcn_mfma_f32_16x16x32_f16(a2[kt], bh, acc2[nt], 0, 0, 0);
                acc2[nt] = __builtin_amdgcn_mfma_f32_16x16x32_f16(a2[kt], be, acc2[nt], 0, 0, 0);
            }

        // L3: out[m] = relu(y2)[m,:] . Wm3 + bm3; reduce over 16 lanes in q-group
        float part[4];
#pragma unroll
        for (int r = 0; r < 4; r++) part[r] = 0.f;
#pragma unroll
        for (int nt = 0; nt < 4; nt++)
#pragma unroll
            for (int r = 0; r < 4; r++)
                part[r] += fmaxf(acc2[nt][r], 0.f) * wm3v[nt];
#pragma unroll
        for (int s = 1; s <= 8; s <<= 1)
#pragma unroll
            for (int r = 0; r < 4; r++) part[r] += __shfl_xor(part[r], s);
        if (p == 0) {
            float4 o = make_float4(part[0] + b3, part[1] + b3, part[2] + b3, part[3] + b3);
            *(float4*)&outv[tile * 16 + q * 4] = o;
        }

        if (!more) break;
        tile = next;
#pragma unroll
        for (int kt = 0; kt < 4; kt++) { za[kt] = zan[kt]; zb[kt] = zbn[kt]; }
    }
}

// ---------------------------------------------------------------------------
extern "C" void kernel_launch(void* const* d_in, const int* in_sizes, int n_in,
                              void* d_out, int out_size, void* d_ws, size_t ws_size,
                              hipStream_t stream) {
    const float* x   = (const float*)d_in[0];
    const int*   src = (const int*)d_in[1];
    const int*   dst = src + kE;
    const int*   ep  = (const int*)d_in[2];
    const float* W1l = (const float*)d_in[3];
    const float* b1l = (const float*)d_in[4];
    const float* W1r = (const float*)d_in[5];
    const float* W2l = (const float*)d_in[6];
    const float* b2l = (const float*)d_in[7];
    const float* W2r = (const float*)d_in[8];
    const float* Wm1 = (const float*)d_in[9];
    const float* bm1 = (const float*)d_in[10];
    const float* Wm2 = (const float*)d_in[11];
    const float* bm2 = (const float*)d_in[12];
    const float* Wm3 = (const float*)d_in[13];
    const float* bm3 = (const float*)d_in[14];
    float* outv = (float*)d_out;

    char* ws = (char*)d_ws;
    size_t off = 0;
    auto alloc = [&](size_t bytes) -> void* {
        void* p = ws + off;
        off += bytes;
        off = (off + 255) & ~(size_t)255;
        return p;
    };
    int*      deg       = (int*)alloc((size_t)kN * 4);
    int*      row_start = (int*)alloc((size_t)(kN + 1) * 4);
    int*      cursor    = (int*)alloc((size_t)kN * 4);
    int*      bsum      = (int*)alloc(512 * 4);
    int*      boff      = (int*)alloc(512 * 4);
    int*      srcs      = (int*)alloc((size_t)kE * 4);
    _Float16* xh        = (_Float16*)alloc((size_t)kN * 128 * 2);
    _Float16* hh        = (_Float16*)alloc((size_t)kN * 128 * 2);
    _Float16* zh        = (_Float16*)alloc((size_t)kN * 128 * 2);
    _Float16* CW1h      = (_Float16*)alloc(128 * 256 * 2);
    _Float16* CW1e      = (_Float16*)alloc(128 * 256 * 2);
    _Float16* CW2h      = (_Float16*)alloc(128 * 256 * 2);
    _Float16* CW2e      = (_Float16*)alloc(128 * 256 * 2);
    _Float16* M1h       = (_Float16*)alloc(128 * 128 * 2);
    _Float16* M1e       = (_Float16*)alloc(128 * 128 * 2);
    _Float16* M2h       = (_Float16*)alloc(64 * 128 * 2);
    _Float16* M2e       = (_Float16*)alloc(64 * 128 * 2);

    // CSR build
    hipMemsetAsync(deg, 0, (size_t)kN * sizeof(int), stream);
    deg_kernel<<<(kE + 255) / 256, 256, 0, stream>>>(dst, deg);
    scan_block_sums<<<NBS, 256, 0, stream>>>(deg, bsum);
    scan_bsums<<<1, 512, 0, stream>>>(bsum, boff);
    scan_write<<<NBS, 256, 0, stream>>>(deg, boff, row_start, cursor);
    fill_kernel<<<(kE + 255) / 256, 256, 0, stream>>>(src, dst, cursor, srcs);

    // Prep: fp16 conversions
    cvt_x_kernel<<<(kN * 128 / 8 + 255) / 256, 256, 0, stream>>>(x, xh);
    cvt_w_kernel<<<352, 256, 0, stream>>>(W1l, W1r, W2l, W2r, Wm1, Wm2,
                                          CW1h, CW1e, CW2h, CW2e, M1h, M1e, M2h, M2e);

    // Two SAGEConv layers (wave-autonomous)
    const int convBlocks = (CTILES + 3) / 4;  // 4 waves/block
    conv_mfma<true><<<convBlocks, 256, 0, stream>>>(xh, row_start, srcs, CW1h, CW1e, b1l, hh);
    conv_mfma<false><<<convBlocks, 256, 0, stream>>>(hh, row_start, srcs, CW2h, CW2e, b2l, zh);

    // Fused decoder: persistent, 768 blocks (3/CU guaranteed resident)
    decoder_mfma<<<768, 256, 0, stream>>>(
        zh, ep, M1h, M1e, bm1, M2h, M2e, bm2, Wm3, bm3, outv);
}

// Round 4
// 779.693 us; speedup vs baseline: 1.6728x; 1.6728x over previous
//
#include <hip/hip_runtime.h>
#include <stdint.h>

typedef _Float16 half8 __attribute__((ext_vector_type(8)));
typedef float float4v __attribute__((ext_vector_type(4)));

// Problem constants
constexpr int kN = 100000;   // nodes
constexpr int kE = 1600000;  // edges
constexpr int kP = 500000;   // pairs
constexpr int NBS = (kN + 255) / 256;  // scan blocks = 391
constexpr int CT2 = kN / 32;           // 3125 conv wave-tiles (32 nodes each, exact)
constexpr int DT2 = kP / 32;           // 15625 decoder wave-tiles (32 pairs each, exact)

// ---------------------------------------------------------------------------
// CSR build
// ---------------------------------------------------------------------------
__global__ void deg_kernel(const int* __restrict__ dst, int* __restrict__ deg) {
    int e = blockIdx.x * blockDim.x + threadIdx.x;
    if (e < kE) atomicAdd(&deg[dst[e]], 1);
}

__global__ void scan_block_sums(const int* __restrict__ deg, int* __restrict__ bsum) {
    __shared__ int red[256];
    int t = threadIdx.x;
    int i = blockIdx.x * 256 + t;
    red[t] = (i < kN) ? deg[i] : 0;
    __syncthreads();
    for (int s = 128; s > 0; s >>= 1) {
        if (t < s) red[t] += red[t + s];
        __syncthreads();
    }
    if (t == 0) bsum[blockIdx.x] = red[0];
}

__global__ void scan_bsums(const int* __restrict__ bsum, int* __restrict__ boff) {
    __shared__ int sm[512];
    int t = threadIdx.x;
    int orig = (t < NBS) ? bsum[t] : 0;
    sm[t] = orig;
    __syncthreads();
    for (int d = 1; d < 512; d <<= 1) {
        int u = (t >= d) ? sm[t - d] : 0;
        __syncthreads();
        sm[t] += u;
        __syncthreads();
    }
    if (t < NBS) boff[t] = sm[t] - orig;  // exclusive
}

__global__ void scan_write(const int* __restrict__ deg, const int* __restrict__ boff,
                           int* __restrict__ row_start, int* __restrict__ cursor) {
    __shared__ int sm[256];
    int t = threadIdx.x;
    int i = blockIdx.x * 256 + t;
    int v = (i < kN) ? deg[i] : 0;
    sm[t] = v;
    __syncthreads();
    for (int d = 1; d < 256; d <<= 1) {
        int u = (t >= d) ? sm[t - d] : 0;
        __syncthreads();
        sm[t] += u;
        __syncthreads();
    }
    int excl = sm[t] - v + boff[blockIdx.x];
    if (i < kN) { row_start[i] = excl; cursor[i] = excl; }
    if (i == kN - 1) row_start[kN] = excl + v;
}

__global__ void fill_kernel(const int* __restrict__ src, const int* __restrict__ dst,
                            int* __restrict__ cursor, int* __restrict__ srcs) {
    int e = blockIdx.x * blockDim.x + threadIdx.x;
    if (e < kE) {
        int p = atomicAdd(&cursor[dst[e]], 1);
        srcs[p] = src[e];
    }
}

// ---------------------------------------------------------------------------
// Prep: x -> fp16; weights -> fp16 hi/lo planes
// ---------------------------------------------------------------------------
__global__ void cvt_x_kernel(const float* __restrict__ x, _Float16* __restrict__ xh) {
    const int i = (blockIdx.x * 256 + threadIdx.x) * 8;
    if (i >= kN * 128) return;
    const float4 a = *(const float4*)&x[i];
    const float4 b = *(const float4*)&x[i + 4];
    half8 v;
    v[0] = (_Float16)a.x; v[1] = (_Float16)a.y; v[2] = (_Float16)a.z; v[3] = (_Float16)a.w;
    v[4] = (_Float16)b.x; v[5] = (_Float16)b.y; v[6] = (_Float16)b.z; v[7] = (_Float16)b.w;
    *(half8*)&xh[i] = v;
}

// CW1/CW2: [128 out][256 k], k<128 -> Wl, k>=128 -> Wr. M1:[128][128], M2:[64][128].
__global__ void cvt_w_kernel(
    const float* __restrict__ W1l, const float* __restrict__ W1r,
    const float* __restrict__ W2l, const float* __restrict__ W2r,
    const float* __restrict__ Wm1, const float* __restrict__ Wm2,
    _Float16* __restrict__ CW1h, _Float16* __restrict__ CW1e,
    _Float16* __restrict__ CW2h, _Float16* __restrict__ CW2e,
    _Float16* __restrict__ M1h,  _Float16* __restrict__ M2h)
{
    const int i = blockIdx.x * 256 + threadIdx.x;
    if (i < 32768) {
        const int o = i >> 8, k = i & 255;
        const float w = (k < 128) ? W1l[o * 128 + k] : W1r[o * 128 + k - 128];
        const _Float16 h = (_Float16)w;
        CW1h[i] = h; CW1e[i] = (_Float16)(w - (float)h);
    } else if (i < 65536) {
        const int j = i - 32768;
        const int o = j >> 8, k = j & 255;
        const float w = (k < 128) ? W2l[o * 128 + k] : W2r[o * 128 + k - 128];
        const _Float16 h = (_Float16)w;
        CW2h[j] = h; CW2e[j] = (_Float16)(w - (float)h);
    } else if (i < 81920) {
        const int j = i - 65536;
        M1h[j] = (_Float16)Wm1[j];
    } else if (i < 90112) {
        const int j = i - 81920;
        M2h[j] = (_Float16)Wm2[j];
    }
}

// ---------------------------------------------------------------------------
// Wave-autonomous fused SAGEConv, 32 nodes/wave, no __syncthreads.
// Gather: 4 groups (q) x 8 sequential nodes, 16 lanes (p) cover 256 B row
// contiguously; idx ring depth 4 + row ring depth 2. Mean -> LDS slice.
// Root rows: frag-direct coalesced loads (consecutive node IDs).
// MFMA: M=32 (2 subtiles), K=256 [mean|root], weights hi+lo from L2.
// LDS: 4 waves x [32][136] fp16 = 34816 B.
// ---------------------------------------------------------------------------
template <bool RELU>
__global__ __launch_bounds__(256, 3) void conv_mfma(
    const _Float16* __restrict__ xin,
    const int* __restrict__ row_start,
    const int* __restrict__ srcs,
    const _Float16* __restrict__ Wh,  // [128][256]
    const _Float16* __restrict__ We,  // [128][256]
    const float* __restrict__ bias,
    _Float16* __restrict__ out)
{
    __shared__ __align__(16) _Float16 stg_all[4 * 32 * 136];
    const int wInB = threadIdx.x >> 6;
    _Float16* stg  = &stg_all[wInB * (32 * 136)];
    const int l = threadIdx.x & 63;
    const int p = l & 15;
    const int q = l >> 4;
    const int tile = blockIdx.x * 4 + wInB;
    if (tile >= CT2) return;

    // Root rows, frag-direct (consecutive rows -> fully coalesced)
    half8 rt[2][4];
#pragma unroll
    for (int m = 0; m < 2; m++)
#pragma unroll
        for (int kt = 0; kt < 4; kt++)
            rt[m][kt] = *(const half8*)&xin[(size_t)(tile * 32 + m * 16 + p) * 128 + kt * 32 + q * 8];

    // Gather-mean: group q handles nodes sub*4+q, lanes p cover dims p*8..p*8+8
    const int c = p * 8;
    for (int sub = 0; sub < 8; sub++) {
        const int n  = tile * 32 + sub * 4 + q;
        const int j0 = row_start[n], j1 = row_start[n + 1];
        const int cnt = j1 - j0;
        float facc[8];
#pragma unroll
        for (int u = 0; u < 8; u++) facc[u] = 0.f;

        int idxq[4];
#pragma unroll
        for (int k = 0; k < 4; k++) idxq[k] = (j0 + k < j1) ? srcs[j0 + k] : 0;
        half8 r0, r1;
#pragma unroll
        for (int u = 0; u < 8; u++) { r0[u] = (_Float16)0.f; r1[u] = (_Float16)0.f; }
        if (cnt > 0) r0 = *(const half8*)&xin[(size_t)idxq[0] * 128 + c];
        if (cnt > 1) r1 = *(const half8*)&xin[(size_t)idxq[1] * 128 + c];

        int j = j0;
        for (; j + 2 < j1; j++) {
            const int inew = (j + 4 < j1) ? srcs[j + 4] : 0;
            const half8 rn = *(const half8*)&xin[(size_t)idxq[2] * 128 + c];
#pragma unroll
            for (int u = 0; u < 8; u++) facc[u] += (float)r0[u];
            r0 = r1; r1 = rn;
            idxq[0] = idxq[1]; idxq[1] = idxq[2]; idxq[2] = idxq[3]; idxq[3] = inew;
        }
        if (j < j1) {
#pragma unroll
            for (int u = 0; u < 8; u++) facc[u] += (float)r0[u];
        }
        if (j + 1 < j1) {
#pragma unroll
            for (int u = 0; u < 8; u++) facc[u] += (float)r1[u];
        }
        const float inv = 1.0f / (float)(cnt > 1 ? cnt : 1);
        half8 hv;
#pragma unroll
        for (int u = 0; u < 8; u++) hv[u] = (_Float16)(facc[u] * inv);
        *(half8*)&stg[(sub * 4 + q) * 136 + c] = hv;
    }

    // A-frags for mean half (same-wave DS in-order: writes above visible)
    half8 amf[2][4];
#pragma unroll
    for (int m = 0; m < 2; m++)
#pragma unroll
        for (int kt = 0; kt < 4; kt++)
            amf[m][kt] = *(const half8*)&stg[(m * 16 + p) * 136 + kt * 32 + q * 8];

    // MFMA: D[32][128] = A[32][256] @ CW[128][256]^T (hi+lo)
    float4v acc[2][8];
#pragma unroll
    for (int nt = 0; nt < 8; nt++) {
        const float b = bias[nt * 16 + p];
#pragma unroll
        for (int m = 0; m < 2; m++) {
            acc[m][nt][0] = b; acc[m][nt][1] = b; acc[m][nt][2] = b; acc[m][nt][3] = b;
        }
    }
#pragma unroll
    for (int kt = 0; kt < 8; kt++) {
        const half8 a0 = (kt < 4) ? amf[0][kt] : rt[0][kt - 4];
        const half8 a1 = (kt < 4) ? amf[1][kt] : rt[1][kt - 4];
#pragma unroll
        for (int nt = 0; nt < 8; nt++) {
            const int widx = (nt * 16 + p) * 256 + kt * 32 + q * 8;
            const half8 bh = *(const half8*)&Wh[widx];
            const half8 be = *(const half8*)&We[widx];
            acc[0][nt] = __builtin_amdgcn_mfma_f32_16x16x32_f16(a0, bh, acc[0][nt], 0, 0, 0);
            acc[0][nt] = __builtin_amdgcn_mfma_f32_16x16x32_f16(a0, be, acc[0][nt], 0, 0, 0);
            acc[1][nt] = __builtin_amdgcn_mfma_f32_16x16x32_f16(a1, bh, acc[1][nt], 0, 0, 0);
            acc[1][nt] = __builtin_amdgcn_mfma_f32_16x16x32_f16(a1, be, acc[1][nt], 0, 0, 0);
        }
    }

    // Epilogue: C-layout -> LDS (reuse slice) -> coalesced row-major store
#pragma unroll
    for (int m = 0; m < 2; m++)
#pragma unroll
        for (int nt = 0; nt < 8; nt++)
#pragma unroll
            for (int r = 0; r < 4; r++) {
                float v = acc[m][nt][r];
                if (RELU) v = fmaxf(v, 0.f);
                stg[(m * 16 + q * 4 + r) * 136 + nt * 16 + p] = (_Float16)v;
            }
#pragma unroll
    for (int it = 0; it < 8; it++) {
        const int row = it * 4 + q;
        *(half8*)&out[(size_t)(tile * 32 + row) * 128 + c] =
            *(const half8*)&stg[row * 136 + c];
    }
}

// ---------------------------------------------------------------------------
// Wave-autonomous fused decoder, 32 pairs/wave, no __syncthreads.
// P1: coalesced row gathers (16 lanes x 16 B per row), products -> LDS slice.
// L1/L2: MFMA with hi-plane weights only (error ~1e-5). L3: dot + reduce.
// LDS: 4 waves x [32][136] fp16 = 34816 B.
// ---------------------------------------------------------------------------
__global__ __launch_bounds__(256, 3) void decoder_mfma(
    const _Float16* __restrict__ z,
    const int* __restrict__ pairs,
    const _Float16* __restrict__ M1h, const float* __restrict__ bm1,
    const _Float16* __restrict__ M2h, const float* __restrict__ bm2,
    const float* __restrict__ Wm3, const float* __restrict__ bm3,
    float* __restrict__ outv)
{
    __shared__ __align__(16) _Float16 buf_all[4 * 32 * 136];
    const int wInB = threadIdx.x >> 6;
    _Float16* buf  = &buf_all[wInB * (32 * 136)];
    const int l = threadIdx.x & 63;
    const int p = l & 15;
    const int q = l >> 4;
    const int tile = blockIdx.x * 4 + wInB;
    if (tile >= DT2) return;
    const int c = p * 8;

    // P1: hp = z[a]*z[b]; batch all idx loads, then all row loads (2 epochs)
    int2 ab[8];
#pragma unroll
    for (int it = 0; it < 8; it++)
        ab[it] = *(const int2*)&pairs[(size_t)(tile * 32 + it * 4 + q) * 2];
    half8 za[8], zb[8];
#pragma unroll
    for (int it = 0; it < 8; it++) {
        za[it] = *(const half8*)&z[(size_t)ab[it].x * 128 + c];
        zb[it] = *(const half8*)&z[(size_t)ab[it].y * 128 + c];
    }
#pragma unroll
    for (int it = 0; it < 8; it++)
        *(half8*)&buf[(it * 4 + q) * 136 + c] = za[it] * zb[it];

    // L1: y1 = relu(hp @ M1^T + bm1), M=32, N=128, K=128
    half8 a1[2][4];
#pragma unroll
    for (int m = 0; m < 2; m++)
#pragma unroll
        for (int kt = 0; kt < 4; kt++)
            a1[m][kt] = *(const half8*)&buf[(m * 16 + p) * 136 + kt * 32 + q * 8];

    float4v acc1[2][8];
#pragma unroll
    for (int nt = 0; nt < 8; nt++) {
        const float b = bm1[nt * 16 + p];
#pragma unroll
        for (int m = 0; m < 2; m++) {
            acc1[m][nt][0] = b; acc1[m][nt][1] = b; acc1[m][nt][2] = b; acc1[m][nt][3] = b;
        }
    }
#pragma unroll
    for (int kt = 0; kt < 4; kt++)
#pragma unroll
        for (int nt = 0; nt < 8; nt++) {
            const half8 bh = *(const half8*)&M1h[(nt * 16 + p) * 128 + kt * 32 + q * 8];
            acc1[0][nt] = __builtin_amdgcn_mfma_f32_16x16x32_f16(a1[0][kt], bh, acc1[0][nt], 0, 0, 0);
            acc1[1][nt] = __builtin_amdgcn_mfma_f32_16x16x32_f16(a1[1][kt], bh, acc1[1][nt], 0, 0, 0);
        }

    // y1 -> LDS (same-wave order: a1 reads already done)
#pragma unroll
    for (int m = 0; m < 2; m++)
#pragma unroll
        for (int nt = 0; nt < 8; nt++)
#pragma unroll
            for (int r = 0; r < 4; r++)
                buf[(m * 16 + q * 4 + r) * 136 + nt * 16 + p] =
                    (_Float16)fmaxf(acc1[m][nt][r], 0.f);

    // L2: y2 = relu(y1 @ M2^T + bm2), N=64, K=128
    half8 a2[2][4];
#pragma unroll
    for (int m = 0; m < 2; m++)
#pragma unroll
        for (int kt = 0; kt < 4; kt++)
            a2[m][kt] = *(const half8*)&buf[(m * 16 + p) * 136 + kt * 32 + q * 8];

    float4v acc2[2][4];
#pragma unroll
    for (int nt = 0; nt < 4; nt++) {
        const float b = bm2[nt * 16 + p];
#pragma unroll
        for (int m = 0; m < 2; m++) {
            acc2[m][nt][0] = b; acc2[m][nt][1] = b; acc2[m][nt][2] = b; acc2[m][nt][3] = b;
        }
    }
#pragma unroll
    for (int kt = 0; kt < 4; kt++)
#pragma unroll
        for (int nt = 0; nt < 4; nt++) {
            const half8 bh = *(const half8*)&M2h[(nt * 16 + p) * 128 + kt * 32 + q * 8];
            acc2[0][nt] = __builtin_amdgcn_mfma_f32_16x16x32_f16(a2[0][kt], bh, acc2[0][nt], 0, 0, 0);
            acc2[1][nt] = __builtin_amdgcn_mfma_f32_16x16x32_f16(a2[1][kt], bh, acc2[1][nt], 0, 0, 0);
        }

    // L3: out = relu(y2) . Wm3 + bm3
    float wm3v[4];
#pragma unroll
    for (int nt = 0; nt < 4; nt++) wm3v[nt] = Wm3[nt * 16 + p];
    const float b3 = bm3[0];
#pragma unroll
    for (int m = 0; m < 2; m++) {
        float part[4];
#pragma unroll
        for (int r = 0; r < 4; r++) part[r] = 0.f;
#pragma unroll
        for (int nt = 0; nt < 4; nt++)
#pragma unroll
            for (int r = 0; r < 4; r++)
                part[r] += fmaxf(acc2[m][nt][r], 0.f) * wm3v[nt];
#pragma unroll
        for (int s = 1; s <= 8; s <<= 1)
#pragma unroll
            for (int r = 0; r < 4; r++) part[r] += __shfl_xor(part[r], s);
        if (p == 0) {
            float4 o = make_float4(part[0] + b3, part[1] + b3, part[2] + b3, part[3] + b3);
            *(float4*)&outv[tile * 32 + m * 16 + q * 4] = o;
        }
    }
}

// ---------------------------------------------------------------------------
extern "C" void kernel_launch(void* const* d_in, const int* in_sizes, int n_in,
                              void* d_out, int out_size, void* d_ws, size_t ws_size,
                              hipStream_t stream) {
    const float* x   = (const float*)d_in[0];
    const int*   src = (const int*)d_in[1];
    const int*   dst = src + kE;
    const int*   ep  = (const int*)d_in[2];
    const float* W1l = (const float*)d_in[3];
    const float* b1l = (const float*)d_in[4];
    const float* W1r = (const float*)d_in[5];
    const float* W2l = (const float*)d_in[6];
    const float* b2l = (const float*)d_in[7];
    const float* W2r = (const float*)d_in[8];
    const float* Wm1 = (const float*)d_in[9];
    const float* bm1 = (const float*)d_in[10];
    const float* Wm2 = (const float*)d_in[11];
    const float* bm2 = (const float*)d_in[12];
    const float* Wm3 = (const float*)d_in[13];
    const float* bm3 = (const float*)d_in[14];
    float* outv = (float*)d_out;

    char* ws = (char*)d_ws;
    size_t off = 0;
    auto alloc = [&](size_t bytes) -> void* {
        void* p = ws + off;
        off += bytes;
        off = (off + 255) & ~(size_t)255;
        return p;
    };
    int*      deg       = (int*)alloc((size_t)kN * 4);
    int*      row_start = (int*)alloc((size_t)(kN + 1) * 4);
    int*      cursor    = (int*)alloc((size_t)kN * 4);
    int*      bsum      = (int*)alloc(512 * 4);
    int*      boff      = (int*)alloc(512 * 4);
    int*      srcs      = (int*)alloc((size_t)kE * 4);
    _Float16* xh        = (_Float16*)alloc((size_t)kN * 128 * 2);
    _Float16* hh        = (_Float16*)alloc((size_t)kN * 128 * 2);
    _Float16* zh        = (_Float16*)alloc((size_t)kN * 128 * 2);
    _Float16* CW1h      = (_Float16*)alloc(128 * 256 * 2);
    _Float16* CW1e      = (_Float16*)alloc(128 * 256 * 2);
    _Float16* CW2h      = (_Float16*)alloc(128 * 256 * 2);
    _Float16* CW2e      = (_Float16*)alloc(128 * 256 * 2);
    _Float16* M1h       = (_Float16*)alloc(128 * 128 * 2);
    _Float16* M2h       = (_Float16*)alloc(64 * 128 * 2);

    // CSR build
    hipMemsetAsync(deg, 0, (size_t)kN * sizeof(int), stream);
    deg_kernel<<<(kE + 255) / 256, 256, 0, stream>>>(dst, deg);
    scan_block_sums<<<NBS, 256, 0, stream>>>(deg, bsum);
    scan_bsums<<<1, 512, 0, stream>>>(bsum, boff);
    scan_write<<<NBS, 256, 0, stream>>>(deg, boff, row_start, cursor);
    fill_kernel<<<(kE + 255) / 256, 256, 0, stream>>>(src, dst, cursor, srcs);

    // Prep: fp16 conversions
    cvt_x_kernel<<<(kN * 128 / 8 + 255) / 256, 256, 0, stream>>>(x, xh);
    cvt_w_kernel<<<352, 256, 0, stream>>>(W1l, W1r, W2l, W2r, Wm1, Wm2,
                                          CW1h, CW1e, CW2h, CW2e, M1h, M2h);

    // Two SAGEConv layers (32 nodes/wave)
    const int convBlocks = (CT2 + 3) / 4;
    conv_mfma<true><<<convBlocks, 256, 0, stream>>>(xh, row_start, srcs, CW1h, CW1e, b1l, hh);
    conv_mfma<false><<<convBlocks, 256, 0, stream>>>(hh, row_start, srcs, CW2h, CW2e, b2l, zh);

    // Fused decoder (32 pairs/wave, hi-plane weights)
    const int decBlocks = (DT2 + 3) / 4;
    decoder_mfma<<<decBlocks, 256, 0, stream>>>(
        zh, ep, M1h, bm1, M2h, bm2, Wm3, bm3, outv);
}

// Round 5
// 686.046 us; speedup vs baseline: 1.9012x; 1.1365x over previous
//
#include <hip/hip_runtime.h>
#include <stdint.h>

typedef _Float16 half8 __attribute__((ext_vector_type(8)));
typedef float float4v __attribute__((ext_vector_type(4)));

// Problem constants
constexpr int kN = 100000;   // nodes
constexpr int kE = 1600000;  // edges
constexpr int kP = 500000;   // pairs
constexpr int NBS = (kN + 255) / 256;  // scan blocks = 391
constexpr int CT2 = kN / 32;           // 3125 conv wave-tiles (32 nodes each, exact)
constexpr int DT2 = kP / 32;           // 15625 decoder wave-tiles (32 pairs each, exact)

// ---------------------------------------------------------------------------
// CSR build
// ---------------------------------------------------------------------------
__global__ void deg_kernel(const int* __restrict__ dst, int* __restrict__ deg) {
    int e = blockIdx.x * blockDim.x + threadIdx.x;
    if (e < kE) atomicAdd(&deg[dst[e]], 1);
}

__global__ void scan_block_sums(const int* __restrict__ deg, int* __restrict__ bsum) {
    __shared__ int red[256];
    int t = threadIdx.x;
    int i = blockIdx.x * 256 + t;
    red[t] = (i < kN) ? deg[i] : 0;
    __syncthreads();
    for (int s = 128; s > 0; s >>= 1) {
        if (t < s) red[t] += red[t + s];
        __syncthreads();
    }
    if (t == 0) bsum[blockIdx.x] = red[0];
}

__global__ void scan_bsums(const int* __restrict__ bsum, int* __restrict__ boff) {
    __shared__ int sm[512];
    int t = threadIdx.x;
    int orig = (t < NBS) ? bsum[t] : 0;
    sm[t] = orig;
    __syncthreads();
    for (int d = 1; d < 512; d <<= 1) {
        int u = (t >= d) ? sm[t - d] : 0;
        __syncthreads();
        sm[t] += u;
        __syncthreads();
    }
    if (t < NBS) boff[t] = sm[t] - orig;  // exclusive
}

__global__ void scan_write(const int* __restrict__ deg, const int* __restrict__ boff,
                           int* __restrict__ row_start, int* __restrict__ cursor) {
    __shared__ int sm[256];
    int t = threadIdx.x;
    int i = blockIdx.x * 256 + t;
    int v = (i < kN) ? deg[i] : 0;
    sm[t] = v;
    __syncthreads();
    for (int d = 1; d < 256; d <<= 1) {
        int u = (t >= d) ? sm[t - d] : 0;
        __syncthreads();
        sm[t] += u;
        __syncthreads();
    }
    int excl = sm[t] - v + boff[blockIdx.x];
    if (i < kN) { row_start[i] = excl; cursor[i] = excl; }
    if (i == kN - 1) row_start[kN] = excl + v;
}

__global__ void fill_kernel(const int* __restrict__ src, const int* __restrict__ dst,
                            int* __restrict__ cursor, int* __restrict__ srcs) {
    int e = blockIdx.x * blockDim.x + threadIdx.x;
    if (e < kE) {
        int p = atomicAdd(&cursor[dst[e]], 1);
        srcs[p] = src[e];
    }
}

// ---------------------------------------------------------------------------
// Prep: x -> fp16; weights -> fp16 hi/lo planes
// ---------------------------------------------------------------------------
__global__ void cvt_x_kernel(const float* __restrict__ x, _Float16* __restrict__ xh) {
    const int i = (blockIdx.x * 256 + threadIdx.x) * 8;
    if (i >= kN * 128) return;
    const float4 a = *(const float4*)&x[i];
    const float4 b = *(const float4*)&x[i + 4];
    half8 v;
    v[0] = (_Float16)a.x; v[1] = (_Float16)a.y; v[2] = (_Float16)a.z; v[3] = (_Float16)a.w;
    v[4] = (_Float16)b.x; v[5] = (_Float16)b.y; v[6] = (_Float16)b.z; v[7] = (_Float16)b.w;
    *(half8*)&xh[i] = v;
}

// CW1/CW2: [128 out][256 k], k<128 -> Wl, k>=128 -> Wr. M1:[128][128], M2:[64][128].
__global__ void cvt_w_kernel(
    const float* __restrict__ W1l, const float* __restrict__ W1r,
    const float* __restrict__ W2l, const float* __restrict__ W2r,
    const float* __restrict__ Wm1, const float* __restrict__ Wm2,
    _Float16* __restrict__ CW1h, _Float16* __restrict__ CW1e,
    _Float16* __restrict__ CW2h, _Float16* __restrict__ CW2e,
    _Float16* __restrict__ M1h,  _Float16* __restrict__ M2h)
{
    const int i = blockIdx.x * 256 + threadIdx.x;
    if (i < 32768) {
        const int o = i >> 8, k = i & 255;
        const float w = (k < 128) ? W1l[o * 128 + k] : W1r[o * 128 + k - 128];
        const _Float16 h = (_Float16)w;
        CW1h[i] = h; CW1e[i] = (_Float16)(w - (float)h);
    } else if (i < 65536) {
        const int j = i - 32768;
        const int o = j >> 8, k = j & 255;
        const float w = (k < 128) ? W2l[o * 128 + k] : W2r[o * 128 + k - 128];
        const _Float16 h = (_Float16)w;
        CW2h[j] = h; CW2e[j] = (_Float16)(w - (float)h);
    } else if (i < 81920) {
        const int j = i - 65536;
        M1h[j] = (_Float16)Wm1[j];
    } else if (i < 90112) {
        const int j = i - 81920;
        M2h[j] = (_Float16)Wm2[j];
    }
}

// ---------------------------------------------------------------------------
// Wave-autonomous fused SAGEConv, 32 nodes/wave, no __syncthreads.
// Gather: per 16-lane group, node's 16 neighbor indices loaded in ONE
// coalesced instruction, broadcast via __shfl, then 16 independent row
// loads in flight (one latency epoch per chunk). Mean -> LDS slice.
// MFMA: M=32 (2 subtiles), K=256 [mean|root], weights hi+lo from L2.
// LDS: 4 waves x [32][136] fp16 = 34816 B.
// ---------------------------------------------------------------------------
template <bool RELU>
__global__ __launch_bounds__(256, 3) void conv_mfma(
    const _Float16* __restrict__ xin,
    const int* __restrict__ row_start,
    const int* __restrict__ srcs,
    const _Float16* __restrict__ Wh,  // [128][256]
    const _Float16* __restrict__ We,  // [128][256]
    const float* __restrict__ bias,
    _Float16* __restrict__ out)
{
    __shared__ __align__(16) _Float16 stg_all[4 * 32 * 136];
    const int wInB = threadIdx.x >> 6;
    _Float16* stg  = &stg_all[wInB * (32 * 136)];
    const int l = threadIdx.x & 63;
    const int p = l & 15;
    const int q = l >> 4;
    const int tile = blockIdx.x * 4 + wInB;
    if (tile >= CT2) return;
    const int c = p * 8;
    const int lbase = l & 48;  // first lane of this 16-lane group

    // Gather-mean: group q handles node sub*4+q; lanes p cover dims p*8..p*8+8.
    for (int sub = 0; sub < 8; sub++) {
        const int n  = tile * 32 + sub * 4 + q;
        const int j0 = row_start[n], j1 = row_start[n + 1];
        const int cnt = j1 - j0;
        float facc[8];
#pragma unroll
        for (int u = 0; u < 8; u++) facc[u] = 0.f;

        for (int jc = j0; jc < j1; jc += 16) {
            const int m = j1 - jc;  // neighbors in this chunk (>=1), uniform in group
            // ONE coalesced idx load for up to 16 neighbors
            const int myidx = (jc + p < j1) ? srcs[jc + p] : 0;
            // Broadcast each index; issue 16 independent row loads
            half8 rows[16];
#pragma unroll
            for (int i = 0; i < 16; i++) {
                const int s = __shfl(myidx, lbase + i);
                rows[i] = *(const half8*)&xin[(size_t)s * 128 + c];
            }
#pragma unroll
            for (int i = 0; i < 16; i++) {
                if (i < m) {
#pragma unroll
                    for (int u = 0; u < 8; u++) facc[u] += (float)rows[i][u];
                }
            }
        }
        const float inv = 1.0f / (float)(cnt > 1 ? cnt : 1);
        half8 hv;
#pragma unroll
        for (int u = 0; u < 8; u++) hv[u] = (_Float16)(facc[u] * inv);
        *(half8*)&stg[(sub * 4 + q) * 136 + c] = hv;
    }

    // Root rows, frag-direct (consecutive rows -> fully coalesced); loaded
    // after gather to keep gather-phase VGPR pressure low.
    half8 rt[2][4];
#pragma unroll
    for (int m = 0; m < 2; m++)
#pragma unroll
        for (int kt = 0; kt < 4; kt++)
            rt[m][kt] = *(const half8*)&xin[(size_t)(tile * 32 + m * 16 + p) * 128 + kt * 32 + q * 8];

    // A-frags for mean half (same-wave DS in-order: writes above visible)
    half8 amf[2][4];
#pragma unroll
    for (int m = 0; m < 2; m++)
#pragma unroll
        for (int kt = 0; kt < 4; kt++)
            amf[m][kt] = *(const half8*)&stg[(m * 16 + p) * 136 + kt * 32 + q * 8];

    // MFMA: D[32][128] = A[32][256] @ CW[128][256]^T (hi+lo)
    float4v acc[2][8];
#pragma unroll
    for (int nt = 0; nt < 8; nt++) {
        const float b = bias[nt * 16 + p];
#pragma unroll
        for (int m = 0; m < 2; m++) {
            acc[m][nt][0] = b; acc[m][nt][1] = b; acc[m][nt][2] = b; acc[m][nt][3] = b;
        }
    }
#pragma unroll
    for (int kt = 0; kt < 8; kt++) {
        const half8 a0 = (kt < 4) ? amf[0][kt] : rt[0][kt - 4];
        const half8 a1 = (kt < 4) ? amf[1][kt] : rt[1][kt - 4];
#pragma unroll
        for (int nt = 0; nt < 8; nt++) {
            const int widx = (nt * 16 + p) * 256 + kt * 32 + q * 8;
            const half8 bh = *(const half8*)&Wh[widx];
            const half8 be = *(const half8*)&We[widx];
            acc[0][nt] = __builtin_amdgcn_mfma_f32_16x16x32_f16(a0, bh, acc[0][nt], 0, 0, 0);
            acc[0][nt] = __builtin_amdgcn_mfma_f32_16x16x32_f16(a0, be, acc[0][nt], 0, 0, 0);
            acc[1][nt] = __builtin_amdgcn_mfma_f32_16x16x32_f16(a1, bh, acc[1][nt], 0, 0, 0);
            acc[1][nt] = __builtin_amdgcn_mfma_f32_16x16x32_f16(a1, be, acc[1][nt], 0, 0, 0);
        }
    }

    // Epilogue: C-layout -> LDS (reuse slice) -> coalesced row-major store
#pragma unroll
    for (int m = 0; m < 2; m++)
#pragma unroll
        for (int nt = 0; nt < 8; nt++)
#pragma unroll
            for (int r = 0; r < 4; r++) {
                float v = acc[m][nt][r];
                if (RELU) v = fmaxf(v, 0.f);
                stg[(m * 16 + q * 4 + r) * 136 + nt * 16 + p] = (_Float16)v;
            }
#pragma unroll
    for (int it = 0; it < 8; it++) {
        const int row = it * 4 + q;
        *(half8*)&out[(size_t)(tile * 32 + row) * 128 + c] =
            *(const half8*)&stg[row * 136 + c];
    }
}

// ---------------------------------------------------------------------------
// Wave-autonomous fused decoder, 32 pairs/wave, no __syncthreads.
// P1: coalesced row gathers (16 lanes x 16 B per row), products -> LDS slice.
// L1/L2: MFMA with hi-plane weights only. L3: dot + reduce.
// LDS: 4 waves x [32][136] fp16 = 34816 B.
// ---------------------------------------------------------------------------
__global__ __launch_bounds__(256, 3) void decoder_mfma(
    const _Float16* __restrict__ z,
    const int* __restrict__ pairs,
    const _Float16* __restrict__ M1h, const float* __restrict__ bm1,
    const _Float16* __restrict__ M2h, const float* __restrict__ bm2,
    const float* __restrict__ Wm3, const float* __restrict__ bm3,
    float* __restrict__ outv)
{
    __shared__ __align__(16) _Float16 buf_all[4 * 32 * 136];
    const int wInB = threadIdx.x >> 6;
    _Float16* buf  = &buf_all[wInB * (32 * 136)];
    const int l = threadIdx.x & 63;
    const int p = l & 15;
    const int q = l >> 4;
    const int tile = blockIdx.x * 4 + wInB;
    if (tile >= DT2) return;
    const int c = p * 8;

    // P1: hp = z[a]*z[b]; batch all idx loads, then all row loads (2 epochs)
    int2 ab[8];
#pragma unroll
    for (int it = 0; it < 8; it++)
        ab[it] = *(const int2*)&pairs[(size_t)(tile * 32 + it * 4 + q) * 2];
    half8 za[8], zb[8];
#pragma unroll
    for (int it = 0; it < 8; it++) {
        za[it] = *(const half8*)&z[(size_t)ab[it].x * 128 + c];
        zb[it] = *(const half8*)&z[(size_t)ab[it].y * 128 + c];
    }
#pragma unroll
    for (int it = 0; it < 8; it++)
        *(half8*)&buf[(it * 4 + q) * 136 + c] = za[it] * zb[it];

    // L1: y1 = relu(hp @ M1^T + bm1), M=32, N=128, K=128
    half8 a1[2][4];
#pragma unroll
    for (int m = 0; m < 2; m++)
#pragma unroll
        for (int kt = 0; kt < 4; kt++)
            a1[m][kt] = *(const half8*)&buf[(m * 16 + p) * 136 + kt * 32 + q * 8];

    float4v acc1[2][8];
#pragma unroll
    for (int nt = 0; nt < 8; nt++) {
        const float b = bm1[nt * 16 + p];
#pragma unroll
        for (int m = 0; m < 2; m++) {
            acc1[m][nt][0] = b; acc1[m][nt][1] = b; acc1[m][nt][2] = b; acc1[m][nt][3] = b;
        }
    }
#pragma unroll
    for (int kt = 0; kt < 4; kt++)
#pragma unroll
        for (int nt = 0; nt < 8; nt++) {
            const half8 bh = *(const half8*)&M1h[(nt * 16 + p) * 128 + kt * 32 + q * 8];
            acc1[0][nt] = __builtin_amdgcn_mfma_f32_16x16x32_f16(a1[0][kt], bh, acc1[0][nt], 0, 0, 0);
            acc1[1][nt] = __builtin_amdgcn_mfma_f32_16x16x32_f16(a1[1][kt], bh, acc1[1][nt], 0, 0, 0);
        }

    // y1 -> LDS (same-wave order: a1 reads already done)
#pragma unroll
    for (int m = 0; m < 2; m++)
#pragma unroll
        for (int nt = 0; nt < 8; nt++)
#pragma unroll
            for (int r = 0; r < 4; r++)
                buf[(m * 16 + q * 4 + r) * 136 + nt * 16 + p] =
                    (_Float16)fmaxf(acc1[m][nt][r], 0.f);

    // L2: y2 = relu(y1 @ M2^T + bm2), N=64, K=128
    half8 a2[2][4];
#pragma unroll
    for (int m = 0; m < 2; m++)
#pragma unroll
        for (int kt = 0; kt < 4; kt++)
            a2[m][kt] = *(const half8*)&buf[(m * 16 + p) * 136 + kt * 32 + q * 8];

    float4v acc2[2][4];
#pragma unroll
    for (int nt = 0; nt < 4; nt++) {
        const float b = bm2[nt * 16 + p];
#pragma unroll
        for (int m = 0; m < 2; m++) {
            acc2[m][nt][0] = b; acc2[m][nt][1] = b; acc2[m][nt][2] = b; acc2[m][nt][3] = b;
        }
    }
#pragma unroll
    for (int kt = 0; kt < 4; kt++)
#pragma unroll
        for (int nt = 0; nt < 4; nt++) {
            const half8 bh = *(const half8*)&M2h[(nt * 16 + p) * 128 + kt * 32 + q * 8];
            acc2[0][nt] = __builtin_amdgcn_mfma_f32_16x16x32_f16(a2[0][kt], bh, acc2[0][nt], 0, 0, 0);
            acc2[1][nt] = __builtin_amdgcn_mfma_f32_16x16x32_f16(a2[1][kt], bh, acc2[1][nt], 0, 0, 0);
        }

    // L3: out = relu(y2) . Wm3 + bm3
    float wm3v[4];
#pragma unroll
    for (int nt = 0; nt < 4; nt++) wm3v[nt] = Wm3[nt * 16 + p];
    const float b3 = bm3[0];
#pragma unroll
    for (int m = 0; m < 2; m++) {
        float part[4];
#pragma unroll
        for (int r = 0; r < 4; r++) part[r] = 0.f;
#pragma unroll
        for (int nt = 0; nt < 4; nt++)
#pragma unroll
            for (int r = 0; r < 4; r++)
                part[r] += fmaxf(acc2[m][nt][r], 0.f) * wm3v[nt];
#pragma unroll
        for (int s = 1; s <= 8; s <<= 1)
#pragma unroll
            for (int r = 0; r < 4; r++) part[r] += __shfl_xor(part[r], s);
        if (p == 0) {
            float4 o = make_float4(part[0] + b3, part[1] + b3, part[2] + b3, part[3] + b3);
            *(float4*)&outv[tile * 32 + m * 16 + q * 4] = o;
        }
    }
}

// ---------------------------------------------------------------------------
extern "C" void kernel_launch(void* const* d_in, const int* in_sizes, int n_in,
                              void* d_out, int out_size, void* d_ws, size_t ws_size,
                              hipStream_t stream) {
    const float* x   = (const float*)d_in[0];
    const int*   src = (const int*)d_in[1];
    const int*   dst = src + kE;
    const int*   ep  = (const int*)d_in[2];
    const float* W1l = (const float*)d_in[3];
    const float* b1l = (const float*)d_in[4];
    const float* W1r = (const float*)d_in[5];
    const float* W2l = (const float*)d_in[6];
    const float* b2l = (const float*)d_in[7];
    const float* W2r = (const float*)d_in[8];
    const float* Wm1 = (const float*)d_in[9];
    const float* bm1 = (const float*)d_in[10];
    const float* Wm2 = (const float*)d_in[11];
    const float* bm2 = (const float*)d_in[12];
    const float* Wm3 = (const float*)d_in[13];
    const float* bm3 = (const float*)d_in[14];
    float* outv = (float*)d_out;

    char* ws = (char*)d_ws;
    size_t off = 0;
    auto alloc = [&](size_t bytes) -> void* {
        void* p = ws + off;
        off += bytes;
        off = (off + 255) & ~(size_t)255;
        return p;
    };
    int*      deg       = (int*)alloc((size_t)kN * 4);
    int*      row_start = (int*)alloc((size_t)(kN + 1) * 4);
    int*      cursor    = (int*)alloc((size_t)kN * 4);
    int*      bsum      = (int*)alloc(512 * 4);
    int*      boff      = (int*)alloc(512 * 4);
    int*      srcs      = (int*)alloc((size_t)kE * 4);
    _Float16* xh        = (_Float16*)alloc((size_t)kN * 128 * 2);
    _Float16* hh        = (_Float16*)alloc((size_t)kN * 128 * 2);
    _Float16* zh        = (_Float16*)alloc((size_t)kN * 128 * 2);
    _Float16* CW1h      = (_Float16*)alloc(128 * 256 * 2);
    _Float16* CW1e      = (_Float16*)alloc(128 * 256 * 2);
    _Float16* CW2h      = (_Float16*)alloc(128 * 256 * 2);
    _Float16* CW2e      = (_Float16*)alloc(128 * 256 * 2);
    _Float16* M1h       = (_Float16*)alloc(128 * 128 * 2);
    _Float16* M2h       = (_Float16*)alloc(64 * 128 * 2);

    // CSR build
    hipMemsetAsync(deg, 0, (size_t)kN * sizeof(int), stream);
    deg_kernel<<<(kE + 255) / 256, 256, 0, stream>>>(dst, deg);
    scan_block_sums<<<NBS, 256, 0, stream>>>(deg, bsum);
    scan_bsums<<<1, 512, 0, stream>>>(bsum, boff);
    scan_write<<<NBS, 256, 0, stream>>>(deg, boff, row_start, cursor);
    fill_kernel<<<(kE + 255) / 256, 256, 0, stream>>>(src, dst, cursor, srcs);

    // Prep: fp16 conversions
    cvt_x_kernel<<<(kN * 128 / 8 + 255) / 256, 256, 0, stream>>>(x, xh);
    cvt_w_kernel<<<352, 256, 0, stream>>>(W1l, W1r, W2l, W2r, Wm1, Wm2,
                                          CW1h, CW1e, CW2h, CW2e, M1h, M2h);

    // Two SAGEConv layers (32 nodes/wave, batched-broadcast gather)
    const int convBlocks = (CT2 + 3) / 4;
    conv_mfma<true><<<convBlocks, 256, 0, stream>>>(xh, row_start, srcs, CW1h, CW1e, b1l, hh);
    conv_mfma<false><<<convBlocks, 256, 0, stream>>>(hh, row_start, srcs, CW2h, CW2e, b2l, zh);

    // Fused decoder (32 pairs/wave, hi-plane weights)
    const int decBlocks = (DT2 + 3) / 4;
    decoder_mfma<<<decBlocks, 256, 0, stream>>>(
        zh, ep, M1h, bm1, M2h, bm2, Wm3, bm3, outv);
}